// Round 4
// baseline (272.636 us; speedup 1.0000x reference)
//
#include <hip/hip_runtime.h>

#define HALO 10
#define NPAIR 76   // staged {u,d} pairs per wave row: 74 used, padded

typedef float v2f __attribute__((ext_vector_type(2)));

// 1D Gaussian, sigma=1.5, 11 taps, normalized (compile-time constants;
// matches the reference's fp32 window to ~1e-7 -- far under threshold)
#define G0 0.00102838f
#define G1 0.00759871f
#define G2 0.03600077f
#define G3 0.10936069f
#define G4 0.21300556f
#define G5 0.26601176f
#define G6 G4
#define G7 G3
#define G8 G2
#define G9 G1
#define G10 G0

// one h-conv tap on a staged {u,d} pair
#define HTAP(Q, GW)  { hm += (Q) * (GW); hs += ((Q) * (Q)) * (GW); }

// R4: (a) double-buffered LDS staging + depth-3 register prefetch.
// R3's counters showed VALUBusy 40% at 922 cy/iter = ~1 wave/SIMD running
// the full latency chain serially; the same-iteration ds_write -> ds_read
// alias forced the reads to wait on the freshly staged row. Now iter i
// READS slot[i&1] (staged last iter) and WRITES slot[(i+1)&1] (row i+1,
// arrived via depth-3 prefetch) -- no alias, reads issue at iter top and
// their ~120cy latency hides under pool/stage/load-issue VALU.
// (b) wave-uniform early exit kills the NI-rounding waste (up to 27% of
// iterations at scales 2-4). Role sets rotate with period 3; the loop body
// is instantiated 12x (12 % 3 == 0 and 12 % 2 == 0 keeps roles and slot
// parity consistent across the outer-loop seam).
// ZERO local arrays in the hot path (SROA-before-unroll lesson).

#define LOADROW(RR, AX, AY, HX, HY)                                  \
    { const float* rx_ = xp + (size_t)(RR) * W;                      \
      const float* ry_ = yp + (size_t)(RR) * W;                      \
      AX = rx_[cl]; AY = ry_[cl];                                    \
      if (lane < HALO) { HX = rx_[chalo]; HY = ry_[chalo]; } }

#define ITER(U, PAX, PAY, PHX, PHY, SAX, SAY, SHX, SHY)              \
  {                                                                  \
    const int i = ii + (U);                                          \
    if (i >= n_iter) break;                                          \
    /* 1) h-conv reads from slot[i&1] == slot[U&1] (no alias w/ stage) */ \
    const v2f* pq = (((U) & 1) ? sB : sA) + lane;                    \
    const v2f q0 = pq[0], q1 = pq[1], q2 = pq[2], q3 = pq[3],        \
              q4 = pq[4], q5 = pq[5], q6 = pq[6], q7 = pq[7],        \
              q8 = pq[8], q9 = pq[9], q10 = pq[10];                  \
    /* 2) fused 2x2 avg-pool from role set P (= raw row i) */        \
    if (do_pool && i < poolrows) {                                   \
        float sx2 = PAX + __shfl_xor(PAX, 1, 64);                    \
        float sy2 = PAY + __shfl_xor(PAY, 1, 64);                    \
        if (i & 1) {                                                 \
            if (par == 0) {                                          \
                const int pr = (r0 + i) >> 1;                        \
                xop[(size_t)pr * Wo + (lane >> 1)] = 0.25f * (prevx + sx2); \
                yop[(size_t)pr * Wo + (lane >> 1)] = 0.25f * (prevy + sy2); \
            }                                                        \
        } else { prevx = sx2; prevy = sy2; }                         \
    }                                                                \
    /* 3) stage row i+1 {u,d} from role set S into slot[(i+1)&1] */  \
    { v2f ud_; ud_.x = SAX + SAY; ud_.y = SAX - SAY;                 \
      (((U) & 1) ? sA : sB)[lane] = ud_;                             \
      if (lane < HALO) {                                             \
          v2f hh_; hh_.x = SHX + SHY; hh_.y = SHX - SHY;             \
          (((U) & 1) ? sA : sB)[64 + lane] = hh_; } }                \
    /* 4) issue loads for row i+3 into the just-freed P regs */      \
    { const int rr_ = min(r0 + i + 3, H - 1);                        \
      LOADROW(rr_, PAX, PAY, PHX, PHY) }                             \
    /* 5) horizontal 11-tap conv (uniform weights) */                \
    v2f hm = {0.f, 0.f}, hs = {0.f, 0.f};                            \
    HTAP(q0, G0)  HTAP(q1, G1)  HTAP(q2, G2)  HTAP(q3, G3)           \
    HTAP(q4, G4)  HTAP(q5, G5)  HTAP(q6, G6)  HTAP(q7, G7)           \
    HTAP(q8, G8)  HTAP(q9, G9)  HTAP(q10, G10)                       \
    /* 6) vertical shift register (renamed away under the unroll) */ \
    Hm0=Hm1; Hm1=Hm2; Hm2=Hm3; Hm3=Hm4; Hm4=Hm5; Hm5=Hm6;           \
    Hm6=Hm7; Hm7=Hm8; Hm8=Hm9; Hm9=Hm10; Hm10=hm;                   \
    Hs0=Hs1; Hs1=Hs2; Hs2=Hs3; Hs3=Hs4; Hs4=Hs5; Hs5=Hs6;           \
    Hs6=Hs7; Hs7=Hs8; Hs8=Hs9; Hs9=Hs10; Hs10=hs;                   \
    /* 7) output row o = i-10 */                                     \
    const int o = i - HALO;                                          \
    if (o >= 0 && o < n_out && colvalid) {                           \
        v2f vm = Hm0*G0; vm += Hm1*G1; vm += Hm2*G2; vm += Hm3*G3;   \
        vm += Hm4*G4; vm += Hm5*G5; vm += Hm6*G6; vm += Hm7*G7;      \
        vm += Hm8*G8; vm += Hm9*G9; vm += Hm10*G10;                  \
        v2f vs = Hs0*G0; vs += Hs1*G1; vs += Hs2*G2; vs += Hs3*G3;   \
        vs += Hs4*G4; vs += Hs5*G5; vs += Hs6*G6; vs += Hs7*G7;      \
        vs += Hs8*G8; vs += Hs9*G9; vs += Hs10*G10;                  \
        const float A = vm.x, B = vm.y;                              \
        const float a2 = A * A, b2 = B * B;                          \
        const float mu_xy = 0.25f * (a2 - b2);                       \
        const float msum  = 0.5f  * (a2 + b2);                       \
        const float sig_s  = 0.5f  * (vs.x + vs.y) - msum;           \
        const float sig_xy = 0.25f * (vs.x - vs.y) - mu_xy;          \
        const float c1 = 1e-4f, c2 = 9e-4f;                          \
        const float cs = (2.f * sig_xy + c2) * __builtin_amdgcn_rcpf(sig_s + c2); \
        const float ssim = (2.f * mu_xy + c1) * __builtin_amdgcn_rcpf(msum + c1) * cs; \
        ssim_sum += ssim;                                            \
        cs_sum += cs;                                                \
    }                                                                \
  }

__global__ __launch_bounds__(256, 3) void ssim_wave_kernel(
    const float* __restrict__ x, const float* __restrict__ y,
    float* __restrict__ xo, float* __restrict__ yo,
    float* __restrict__ acc, int H, int W, int ROWS, int do_pool)
{
    const int OH = H - HALO, OW = W - HALO;
    const int nc = blockIdx.z;
    const int tid = threadIdx.x;
    const int wave = tid >> 6, lane = tid & 63;
    const int col0 = blockIdx.x * 64;
    const int r0 = (blockIdx.y * 4 + wave) * ROWS;

    const int c = col0 + lane;
    const bool colvalid = (c < OW);
    const int cl = min(c, W - 1);
    const int chalo = min(col0 + 64 + lane, W - 1);

    const int n_out = min(ROWS, OH - r0);
    const int poolrows = do_pool ? min(ROWS, H - r0) : 0;
    const int n_iter = max(n_out > 0 ? n_out + HALO : 0, poolrows);

    const float* xp = x + (size_t)nc * H * W;
    const float* yp = y + (size_t)nc * H * W;

    __shared__ v2f sUD[4][2][NPAIR];
    v2f* sA = sUD[wave][0];
    v2f* sB = sUD[wave][1];

    // vertical shift register: slot j holds packed h-conv of input row o+j
    v2f Hm0={0.f,0.f}, Hm1=Hm0, Hm2=Hm0, Hm3=Hm0, Hm4=Hm0, Hm5=Hm0,
        Hm6=Hm0, Hm7=Hm0, Hm8=Hm0, Hm9=Hm0, Hm10=Hm0;
    v2f Hs0=Hm0, Hs1=Hm0, Hs2=Hm0, Hs3=Hm0, Hs4=Hm0, Hs5=Hm0,
        Hs6=Hm0, Hs7=Hm0, Hs8=Hm0, Hs9=Hm0, Hs10=Hm0;

    float ssim_sum = 0.f, cs_sum = 0.f;

    // depth-3 prefetch role sets: at iter i, P=set[i%3] holds raw row i
    // (pool input + reload target), S=set[(i+1)%3] holds row i+1 (stage src)
    float ax0=0.f, ay0=0.f, ahx0=0.f, ahy0=0.f;
    float ax1=0.f, ay1=0.f, ahx1=0.f, ahy1=0.f;
    float ax2=0.f, ay2=0.f, ahx2=0.f, ahy2=0.f;
    float prevx = 0.f, prevy = 0.f;

    const int Wo = W >> 1;
    float* xop = xo + (size_t)nc * (H >> 1) * Wo + (col0 >> 1);
    float* yop = yo + (size_t)nc * (H >> 1) * Wo + (col0 >> 1);
    const int par = lane & 1;

    if (n_iter > 0) {
        // prologue: rows r0, r0+1, r0+2 -> sets 0,1,2
        LOADROW(r0, ax0, ay0, ahx0, ahy0)
        { const int r1_ = min(r0 + 1, H - 1); LOADROW(r1_, ax1, ay1, ahx1, ahy1) }
        { const int r2_ = min(r0 + 2, H - 1); LOADROW(r2_, ax2, ay2, ahx2, ahy2) }
        // pre-stage row r0 into slot A
        { v2f ud_; ud_.x = ax0 + ay0; ud_.y = ax0 - ay0; sA[lane] = ud_;
          if (lane < HALO) {
              v2f hh_; hh_.x = ahx0 + ahy0; hh_.y = ahx0 - ahy0;
              sA[64 + lane] = hh_; } }

        for (int ii = 0; ii < n_iter; ii += 12) {
            ITER(0,  ax0, ay0, ahx0, ahy0,  ax1, ay1, ahx1, ahy1)
            ITER(1,  ax1, ay1, ahx1, ahy1,  ax2, ay2, ahx2, ahy2)
            ITER(2,  ax2, ay2, ahx2, ahy2,  ax0, ay0, ahx0, ahy0)
            ITER(3,  ax0, ay0, ahx0, ahy0,  ax1, ay1, ahx1, ahy1)
            ITER(4,  ax1, ay1, ahx1, ahy1,  ax2, ay2, ahx2, ahy2)
            ITER(5,  ax2, ay2, ahx2, ahy2,  ax0, ay0, ahx0, ahy0)
            ITER(6,  ax0, ay0, ahx0, ahy0,  ax1, ay1, ahx1, ahy1)
            ITER(7,  ax1, ay1, ahx1, ahy1,  ax2, ay2, ahx2, ahy2)
            ITER(8,  ax2, ay2, ahx2, ahy2,  ax0, ay0, ahx0, ahy0)
            ITER(9,  ax0, ay0, ahx0, ahy0,  ax1, ay1, ahx1, ahy1)
            ITER(10, ax1, ay1, ahx1, ahy1,  ax2, ay2, ahx2, ahy2)
            ITER(11, ax2, ay2, ahx2, ahy2,  ax0, ay0, ahx0, ahy0)
        }
    }

    // wave-local reduction + one atomic pair per wave
#pragma unroll
    for (int off = 32; off > 0; off >>= 1) {
        ssim_sum += __shfl_down(ssim_sum, off, 64);
        cs_sum   += __shfl_down(cs_sum,   off, 64);
    }
    if (lane == 0) {
        atomicAdd(&acc[nc * 2 + 0], ssim_sum);
        atomicAdd(&acc[nc * 2 + 1], cs_sum);
    }
}

// Combine the 5 scales: prod_s val_s^{w_s}, mean over the 48 (n,c) pairs.
__global__ void finalize_kernel(const float* __restrict__ acc,
                                const float* __restrict__ weights,
                                float* __restrict__ out)
{
    int t = threadIdx.x;  // 64 threads
    float v = 0.f;
    if (t < 48) {
        float prod = 1.f;
#pragma unroll
        for (int s = 0; s < 5; ++s) {
            int O = (512 >> s) - HALO;
            float inv = 1.f / ((float)O * (float)O);
            float ssim = acc[s * 96 + t * 2 + 0] * inv;
            float cs   = acc[s * 96 + t * 2 + 1] * inv;
            float val = (s < 4) ? fmaxf(cs, 0.f) : ssim;  // mcs[:-1] + [ssim]
            prod *= powf(val, weights[s]);
        }
        v = prod;
    }
#pragma unroll
    for (int off = 32; off > 0; off >>= 1) v += __shfl_down(v, off, 64);
    if (t == 0) out[0] = v * (1.f / 48.f);
}

extern "C" void kernel_launch(void* const* d_in, const int* in_sizes, int n_in,
                              void* d_out, int out_size, void* d_ws, size_t ws_size,
                              hipStream_t stream) {
    const float* x = (const float*)d_in[0];       // (16,3,512,512)
    const float* y = (const float*)d_in[1];       // (16,3,512,512)
    const float* weights = (const float*)d_in[3]; // (5,)
    float* out = (float*)d_out;
    float* ws = (float*)d_ws;

    // workspace layout (floats):
    //   [0,480)   : acc[5 scales][48 nc][2]   (ssim_sum, cs_sum)
    //   [512, ..) : downsampled pyramid x/y per scale
    float* acc = ws;
    float* xs1 = ws + 512;
    float* ys1 = xs1 + (size_t)48 * 256 * 256;
    float* xs2 = ys1 + (size_t)48 * 256 * 256;
    float* ys2 = xs2 + (size_t)48 * 128 * 128;
    float* xs3 = ys2 + (size_t)48 * 128 * 128;
    float* ys3 = xs3 + (size_t)48 * 64 * 64;
    float* xs4 = ys3 + (size_t)48 * 64 * 64;
    float* ys4 = xs4 + (size_t)48 * 32 * 32;

    hipMemsetAsync(acc, 0, 480 * sizeof(float), stream);

    dim3 blk(256);
    // R4 tail regrids under the "~1 block/CU at a time" model (R1/R3
    // evidence): wall(scale) ~ ceil(blocks/256) * n_iter * chain.
    //   s0: 768 blk, 3 rounds x 74      (unchanged -- lowest halo overhead)
    //   s1: 192 blk, 1 round  x 74      (was 384 blk = 1.5 rounds x 42 = 84)
    //   s2: 192 blk, 1 round  x 26      (early-exit trims NI 33 -> 26)
    //   s3: 192 blk, 1 round  x 14      (was 96 blk x 22)
    //   s4:  96 blk, 1 round  x 14      (was 48 blk x 22)
    ssim_wave_kernel<<<dim3(8, 2, 48), blk, 0, stream>>>(x, y, xs1, ys1, acc + 0 * 96, 512, 512, 64, 1);
    ssim_wave_kernel<<<dim3(4, 1, 48), blk, 0, stream>>>(xs1, ys1, xs2, ys2, acc + 1 * 96, 256, 256, 64, 1);
    ssim_wave_kernel<<<dim3(2, 2, 48), blk, 0, stream>>>(xs2, ys2, xs3, ys3, acc + 2 * 96, 128, 128, 16, 1);
    ssim_wave_kernel<<<dim3(1, 4, 48), blk, 0, stream>>>(xs3, ys3, xs4, ys4, acc + 3 * 96, 64, 64, 4, 1);
    ssim_wave_kernel<<<dim3(1, 2, 48), blk, 0, stream>>>(xs4, ys4, nullptr, nullptr, acc + 4 * 96, 32, 32, 4, 0);

    finalize_kernel<<<dim3(1), dim3(64), 0, stream>>>(acc, weights, out);
}